// Round 11
// baseline (212.122 us; speedup 1.0000x reference)
//
#include <hip/hip_runtime.h>
#include <math.h>
#include <stdint.h>

#define EPS 1e-5f

typedef __attribute__((ext_vector_type(8))) short bf16x8;
typedef __attribute__((ext_vector_type(4))) float f32x4;

union FragU {
    bf16x8 v;
    ushort u[8];
};

__device__ __forceinline__ ushort f2bf(float f)
{
    union { float f; uint u; } v; v.f = f;
    uint r = v.u + 0x7FFF + ((v.u >> 16) & 1);   // RNE
    return (ushort)(r >> 16);
}
__device__ __forceinline__ float bf2f(ushort u)
{
    union { uint u; float f; } v; v.u = (uint)u << 16;
    return v.f;
}
__device__ __forceinline__ uint packbf2(float lo, float hi)
{
    return (uint)f2bf(lo) | ((uint)f2bf(hi) << 16);
}

#define MFMA(a, b, c) __builtin_amdgcn_mfma_f32_16x16x32_bf16((a), (b), (c), 0, 0, 0)

#define PART_BLOCKS 128   // partition chunks (hist role / k_part must agree)
#define FP_BLOCKS   209   // fuse-pack role blocks (209*4 = 836 >= 833 units)

// 256-thread block exclusive scan; also returns block total.
__device__ __forceinline__ int blockScanExcl(int v, int* wsum, int* tot)
{
    int lane = threadIdx.x & 63, wv = threadIdx.x >> 6;
    int inc = v;
#pragma unroll
    for (int off = 1; off < 64; off <<= 1) {
        int u = __shfl_up(inc, off);
        if (lane >= off) inc += u;
    }
    __syncthreads();
    if (lane == 63) wsum[wv] = inc;
    __syncthreads();
    int add = 0;
#pragma unroll
    for (int i = 0; i < 4; ++i)
        if (i < wv) add += wsum[i];
    *tot = wsum[0] + wsum[1] + wsum[2] + wsum[3];
    return inc + add - v;
}

// ---------------------------------------------------------------------------
// K_preh: triple-role kernel (all roles independent).
//  [0, NWB2):                pre-MLP MFMA, 16 nodes/wave (64/block).
//  [NWB2, NWB2+PART):        per-chunk LDS histogram of dst>>8.
//  [NWB2+PART, +FP_BLOCKS):  fuse post@lin -> Wp bf16 B-frags; bc.
// ---------------------------------------------------------------------------
__global__ __launch_bounds__(256) void k_preh(
    const float* __restrict__ x, const float* __restrict__ pre_w,
    const float* __restrict__ pre_b, const int* __restrict__ ei,
    const float* __restrict__ post_w, const float* __restrict__ post_b,
    const float* __restrict__ lin_w, const float* __restrict__ lin_b,
    ushort* __restrict__ Ab, ushort* __restrict__ Bb,
    int* __restrict__ hist, ushort* __restrict__ Wp, float* __restrict__ bc,
    int N, int E, int NWB2)
{
    int t = threadIdx.x;

    if (blockIdx.x >= NWB2 + PART_BLOCKS) {
        // ---- fuse-pack role ----
        int unit = (blockIdx.x - NWB2 - PART_BLOCKS) * 4 + (t >> 6);
        int j = t & 63;
        if (unit > 832) return;
        if (unit < 832) {
            int r = unit;
            float acc = 0.f;
            for (int k = 0; k < 64; ++k)
                acc = fmaf(post_w[r * 64 + k], lin_w[k * 64 + j], acc);
            int tile, kk;
            if (r < 64) { tile = (r >> 5) * 4 + (j >> 4); kk = r & 31; }
            else {
                int g = (r - 64) >> 8, ka = (r - 64) & 255;
                tile = 8 + (g * 8 + (ka >> 5)) * 4 + (j >> 4); kk = ka & 31;
            }
            int ln = (j & 15) | ((kk >> 3) << 4);
            Wp[tile * 512 + ln * 8 + (kk & 7)] = f2bf(acc);
        } else {
            float a = lin_b[j];
            for (int k = 0; k < 64; ++k)
                a = fmaf(post_b[k], lin_w[k * 64 + j], a);
            bc[j] = a;
        }
        return;
    }

    if (blockIdx.x >= NWB2) {
        // ---- histogram role ----
        __shared__ int lh[256];
        int blk = blockIdx.x - NWB2;
        lh[t] = 0;
        __syncthreads();
        int chunk = (E + PART_BLOCKS - 1) / PART_BLOCKS;
        int c0 = blk * chunk, c1 = min(E, c0 + chunk);
        for (int e = c0 + t; e < c1; e += 256) {
            int dst = ei[E + e];
            if ((unsigned)dst < (unsigned)N) atomicAdd(&lh[dst >> 8], 1);
        }
        __syncthreads();
        hist[blk * 256 + t] = lh[t];
        return;
    }

    // ---- pre-MLP role: 64 nodes/block, 16 nodes/wave ----
    __shared__ ushort pw[16 * 512];
    for (int idx = t; idx < 8192; idx += 256) {
        int kin = idx >> 7, o = idx & 127;
        float v = (o < 64) ? pre_w[kin * 64 + o]
                           : pre_w[(64 + kin) * 64 + (o - 64)];
        int kk = kin & 31;
        int tile = (kin >> 5) * 8 + (o >> 4);
        int ln = (o & 15) | ((kk >> 3) << 4);
        pw[tile * 512 + ln * 8 + (kk & 7)] = f2bf(v);
    }
    __syncthreads();

    int w = t >> 6, lane = t & 63;
    int nb = blockIdx.x * 64 + w * 16;
    if (nb >= N) return;
    int lr = lane & 15, lk = lane >> 4;

    f32x4 acc[8] = {};
#pragma unroll
    for (int ks = 0; ks < 2; ++ks) {
        FragU A0;
        {
            int r0 = min(nb + lr, N - 1);
            const float* p0 = &x[r0 * 64 + ks * 32 + lk * 8];
            float4 a0 = *reinterpret_cast<const float4*>(p0);
            float4 a1 = *reinterpret_cast<const float4*>(p0 + 4);
            A0.u[0] = f2bf(a0.x); A0.u[1] = f2bf(a0.y);
            A0.u[2] = f2bf(a0.z); A0.u[3] = f2bf(a0.w);
            A0.u[4] = f2bf(a1.x); A0.u[5] = f2bf(a1.y);
            A0.u[6] = f2bf(a1.z); A0.u[7] = f2bf(a1.w);
        }
#pragma unroll
        for (int jt = 0; jt < 8; ++jt) {
            bf16x8 B = *reinterpret_cast<const bf16x8*>(
                &pw[(ks * 8 + jt) * 512 + lane * 8]);
            acc[jt] = MFMA(A0.v, B, acc[jt]);
        }
    }
#pragma unroll
    for (int jt = 0; jt < 8; ++jt) {
        int o = jt * 16 + lr;
#pragma unroll
        for (int rg = 0; rg < 4; ++rg) {
            int r = nb + lk * 4 + rg;
            if (r < N) {
                float v = acc[jt][rg];
                if (o < 64) Ab[r * 64 + o] = f2bf(v + pre_b[o]);
                else        Bb[r * 64 + (o - 64)] = f2bf(v);
            }
        }
    }
}

// ---------------------------------------------------------------------------
// K_part: partition with inlined scans (round 10, unchanged).
// ---------------------------------------------------------------------------
__global__ __launch_bounds__(256) void k_part(
    const int* __restrict__ ei, const int* __restrict__ hist,
    int* __restrict__ bstart, uint* __restrict__ staged,
    int* __restrict__ offsets, float* __restrict__ avg_acc, int E, int N)
{
    __shared__ int cur[256];
    __shared__ int wsum[4];
    int t = threadIdx.x, blk = blockIdx.x;

    int pre = 0, tot = 0;
    for (int b = 0; b < PART_BLOCKS; ++b) {
        int h = hist[b * 256 + t];
        pre += (b < blk) ? h : 0;
        tot += h;
    }
    int grand;
    int bs = blockScanExcl(tot, wsum, &grand);
    cur[t] = bs + pre;
    if (blk == 0) {
        bstart[t] = bs;
        if (t == 255) { bstart[256] = grand; offsets[N] = grand; }
        if (t == 0) *avg_acc = 0.f;
    }
    __syncthreads();

    int chunk = (E + PART_BLOCKS - 1) / PART_BLOCKS;
    int c0 = blk * chunk, c1 = min(E, c0 + chunk);
    for (int e = c0 + t; e < c1; e += 256) {
        int src = ei[e];
        int dst = ei[E + e];
        if ((unsigned)dst < (unsigned)N) {
            if ((unsigned)src >= (unsigned)N) src = 0;
            int pos = atomicAdd(&cur[dst >> 8], 1);
            staged[pos] = (uint)src | ((uint)(dst & 255) << 16);
        }
    }
}

// ---------------------------------------------------------------------------
// K_place: one block per bucket (round 10, unchanged).
// ---------------------------------------------------------------------------
__global__ __launch_bounds__(256) void k_place(
    const uint* __restrict__ staged, const int* __restrict__ bucketStart,
    ushort* __restrict__ csr16, int* __restrict__ offsets,
    float* __restrict__ avg_acc, int N)
{
    __shared__ int cnt[256];
    __shared__ int wsum[4];
    __shared__ float fl[4];
    int t = threadIdx.x, lane = t & 63, wv = t >> 6;
    int b = blockIdx.x;
    int s0 = bucketStart[b], s1 = bucketStart[b + 1];

    cnt[t] = 0;
    __syncthreads();
    for (int i = s0 + t; i < s1; i += 256)
        atomicAdd(&cnt[(staged[i] >> 16) & 255], 1);
    __syncthreads();

    int d = cnt[t];
    int v = d;
#pragma unroll
    for (int off = 1; off < 64; off <<= 1) {
        int u = __shfl_up(v, off);
        if (lane >= off) v += u;
    }
    if (lane == 63) wsum[wv] = v;
    __syncthreads();
    int wvoff = 0;
#pragma unroll
    for (int i = 0; i < 4; ++i)
        if (i < wv) wvoff += wsum[i];
    int excl = wvoff + v - d;

    int node = b * 256 + t;
    if (node < N) offsets[node] = s0 + excl;

    float sl = (node < N) ? logf((float)d + 1.0f) : 0.f;
    for (int off = 32; off; off >>= 1) sl += __shfl_down(sl, off);
    if (lane == 0) fl[wv] = sl;

    cnt[t] = excl;            // placement cursor
    __syncthreads();
    if (t == 0) atomicAdd(avg_acc, fl[0] + fl[1] + fl[2] + fl[3]);

    for (int i = s0 + t; i < s1; i += 256) {
        uint ev = staged[i];
        int p = atomicAdd(&cnt[(ev >> 16) & 255], 1);
        csr16[s0 + p] = (ushort)(ev & 0xFFFFu);
    }
}

// ---------------------------------------------------------------------------
// K6: per-node aggregation, quarter-wave-per-edge (uint2 loads).
//   16 lanes x 8B = one 128B B-row per lane-group; 4 edges per load quad.
//   Lane owns a feature QUAD; B-only stats (A folded at finalize).
// ---------------------------------------------------------------------------
__global__ __launch_bounds__(256) void k_aggregate(
    const ushort* __restrict__ Ab, const ushort* __restrict__ Bb,
    const int* __restrict__ offsets, const ushort* __restrict__ csr16,
    const float* __restrict__ avg_sum, ushort* __restrict__ aggs,
    float* __restrict__ amp, float* __restrict__ att, int N)
{
    int wave = threadIdx.x >> 6, lane = threadIdx.x & 63;
    int n = blockIdx.x * 4 + wave;
    if (n >= N) return;

    int off0 = offsets[n], off1 = offsets[n + 1];
    int d = off1 - off0;
    int hq = lane & 15;          // feature-quad index (features hq*4..hq*4+3)
    int which = lane >> 4;       // 0..3: edge slot within quad

    float s0 = 0.f, s1 = 0.f, s2 = 0.f, s3 = 0.f;
    float q0 = 0.f, q1 = 0.f, q2 = 0.f, q3 = 0.f;
    float mn0 = 3.4e38f, mn1 = 3.4e38f, mn2 = 3.4e38f, mn3 = 3.4e38f;
    float mx0 = -3.4e38f, mx1 = -3.4e38f, mx2 = -3.4e38f, mx3 = -3.4e38f;

#define UPD(bv)                                                         \
    {                                                                   \
        float m0 = bf2f((ushort)((bv).x & 0xFFFFu));                    \
        float m1 = bf2f((ushort)((bv).x >> 16));                        \
        float m2 = bf2f((ushort)((bv).y & 0xFFFFu));                    \
        float m3 = bf2f((ushort)((bv).y >> 16));                        \
        s0 += m0; q0 = fmaf(m0, m0, q0);                                \
        mn0 = fminf(mn0, m0); mx0 = fmaxf(mx0, m0);                     \
        s1 += m1; q1 = fmaf(m1, m1, q1);                                \
        mn1 = fminf(mn1, m1); mx1 = fmaxf(mx1, m1);                     \
        s2 += m2; q2 = fmaf(m2, m2, q2);                                \
        mn2 = fminf(mn2, m2); mx2 = fmaxf(mx2, m2);                     \
        s3 += m3; q3 = fmaf(m3, m3, q3);                                \
        mn3 = fminf(mn3, m3); mx3 = fmaxf(mx3, m3);                     \
    }

    for (int base = off0; base < off1; base += 64) {
        int cnt = min(64, off1 - base);
        int s_idx = 0;
        if (lane < cnt) s_idx = (int)csr16[base + lane];
        int i = 0;
        for (; i + 15 < cnt; i += 16) {
            int sA = __shfl(s_idx, i + 0 + which);
            int sB = __shfl(s_idx, i + 4 + which);
            int sC = __shfl(s_idx, i + 8 + which);
            int sD = __shfl(s_idx, i + 12 + which);
            uint2 bA = *reinterpret_cast<const uint2*>(&Bb[(size_t)sA * 64 + hq * 4]);
            uint2 bB = *reinterpret_cast<const uint2*>(&Bb[(size_t)sB * 64 + hq * 4]);
            uint2 bC = *reinterpret_cast<const uint2*>(&Bb[(size_t)sC * 64 + hq * 4]);
            uint2 bD = *reinterpret_cast<const uint2*>(&Bb[(size_t)sD * 64 + hq * 4]);
            UPD(bA); UPD(bB); UPD(bC); UPD(bD);
        }
        for (; i < cnt; i += 4) {
            int sl = i + which;
            int sj = __shfl(s_idx, min(sl, 63));
            uint2 bv = *reinterpret_cast<const uint2*>(&Bb[(size_t)sj * 64 + hq * 4]);
            if (sl < cnt) UPD(bv);
        }
    }
#undef UPD

    // combine the 4 lane-groups (xor 16, then 32)
#define CMB(op, v)  v = op(v, __shfl_xor(v, 16)); v = op(v, __shfl_xor(v, 32));
#define ADDF(a, b) ((a) + (b))
    CMB(ADDF, s0) CMB(ADDF, s1) CMB(ADDF, s2) CMB(ADDF, s3)
    CMB(ADDF, q0) CMB(ADDF, q1) CMB(ADDF, q2) CMB(ADDF, q3)
    CMB(fminf, mn0) CMB(fminf, mn1) CMB(fminf, mn2) CMB(fminf, mn3)
    CMB(fmaxf, mx0) CMB(fmaxf, mx1) CMB(fmaxf, mx2) CMB(fmaxf, mx3)
#undef CMB
#undef ADDF

    uint2 av = *reinterpret_cast<const uint2*>(&Ab[(size_t)n * 64 + hq * 4]);
    float a0 = bf2f((ushort)(av.x & 0xFFFFu));
    float a1 = bf2f((ushort)(av.x >> 16));
    float a2 = bf2f((ushort)(av.y & 0xFFFFu));
    float a3 = bf2f((ushort)(av.y >> 16));

    float dc = (d > 0) ? (float)d : 1.0f;
    float rdc = 1.0f / dc;
    float mB0 = s0 * rdc, mB1 = s1 * rdc, mB2 = s2 * rdc, mB3 = s3 * rdc;
    float std0 = sqrtf(fmaxf(q0 * rdc - mB0 * mB0, 0.f) + EPS);
    float std1 = sqrtf(fmaxf(q1 * rdc - mB1 * mB1, 0.f) + EPS);
    float std2 = sqrtf(fmaxf(q2 * rdc - mB2 * mB2, 0.f) + EPS);
    float std3 = sqrtf(fmaxf(q3 * rdc - mB3 * mB3, 0.f) + EPS);
    float mean0 = a0 + mB0, mean1 = a1 + mB1, mean2 = a2 + mB2, mean3 = a3 + mB3;
    float mnF0 = a0 + mn0, mnF1 = a1 + mn1, mnF2 = a2 + mn2, mnF3 = a3 + mn3;
    float mxF0 = a0 + mx0, mxF1 = a1 + mx1, mxF2 = a2 + mx2, mxF3 = a3 + mx3;
    if (d == 0) {
        mean0 = mean1 = mean2 = mean3 = 0.f;
        mnF0 = mnF1 = mnF2 = mnF3 = 0.f;
        mxF0 = mxF1 = mxF2 = mxF3 = 0.f;
    }

    if (lane < 16) {
        uint2* ag = reinterpret_cast<uint2*>(&aggs[(size_t)n * 256]);
        ag[0 * 16 + hq] = make_uint2(packbf2(mean0, mean1), packbf2(mean2, mean3));
        ag[1 * 16 + hq] = make_uint2(packbf2(mnF0, mnF1), packbf2(mnF2, mnF3));
        ag[2 * 16 + hq] = make_uint2(packbf2(mxF0, mxF1), packbf2(mxF2, mxF3));
        ag[3 * 16 + hq] = make_uint2(packbf2(std0, std1), packbf2(std2, std3));
    }
    if (lane == 0) {
        float avg = *avg_sum / (float)N;
        float dlog = logf(dc + 1.0f);
        amp[n] = dlog / avg;
        att[n] = avg / dlog;
    }
}

// ---------------------------------------------------------------------------
// K7: output GEMM via bf16 MFMA — 16 nodes/wave (2x TLP vs round 10).
// ---------------------------------------------------------------------------
__global__ __launch_bounds__(256) void k_out_gemm(
    const float* __restrict__ x, const ushort* __restrict__ aggs,
    const float* __restrict__ amp, const float* __restrict__ att,
    const ushort* __restrict__ Wp, const float* __restrict__ bc,
    float* __restrict__ out, int N)
{
    int w = threadIdx.x >> 6, lane = threadIdx.x & 63;
    int nb = (blockIdx.x * 4 + w) * 16;
    if (nb >= N) return;
    int lr = lane & 15, lk = lane >> 4;

    f32x4 accP[4] = {};
    f32x4 accA[4] = {};
    f32x4 accT[4] = {};

    // ---- x chunk (K=64, W0 only) ----
#pragma unroll
    for (int ks = 0; ks < 2; ++ks) {
        FragU A0;
        {
            int r0 = min(nb + lr, N - 1);
            const float* p0 = &x[r0 * 64 + ks * 32 + lk * 8];
            float4 a0 = *reinterpret_cast<const float4*>(p0);
            float4 a1 = *reinterpret_cast<const float4*>(p0 + 4);
            A0.u[0] = f2bf(a0.x); A0.u[1] = f2bf(a0.y);
            A0.u[2] = f2bf(a0.z); A0.u[3] = f2bf(a0.w);
            A0.u[4] = f2bf(a1.x); A0.u[5] = f2bf(a1.y);
            A0.u[6] = f2bf(a1.z); A0.u[7] = f2bf(a1.w);
        }
#pragma unroll
        for (int jt = 0; jt < 4; ++jt) {
            bf16x8 B = *reinterpret_cast<const bf16x8*>(
                &Wp[(ks * 4 + jt) * 512 + lane * 8]);
            accP[jt] = MFMA(A0.v, B, accP[jt]);
        }
    }

    // ---- aggs chunks (K=256, W1/W2/W3) ----
#pragma unroll 2
    for (int ks = 0; ks < 8; ++ks) {
        bf16x8 A0 = *reinterpret_cast<const bf16x8*>(
            &aggs[(size_t)(nb + lr) * 256 + ks * 32 + lk * 8]);
#pragma unroll
        for (int jt = 0; jt < 4; ++jt) {
            bf16x8 B0 = *reinterpret_cast<const bf16x8*>(
                &Wp[(8 + (0 * 8 + ks) * 4 + jt) * 512 + lane * 8]);
            bf16x8 B1 = *reinterpret_cast<const bf16x8*>(
                &Wp[(8 + (1 * 8 + ks) * 4 + jt) * 512 + lane * 8]);
            bf16x8 B2 = *reinterpret_cast<const bf16x8*>(
                &Wp[(8 + (2 * 8 + ks) * 4 + jt) * 512 + lane * 8]);
            accP[jt] = MFMA(A0, B0, accP[jt]);
            accA[jt] = MFMA(A0, B1, accA[jt]);
            accT[jt] = MFMA(A0, B2, accT[jt]);
        }
    }

    // ---- epilogue ----
    int rb = nb + lk * 4;
    float am[4], at[4];
#pragma unroll
    for (int rg = 0; rg < 4; ++rg) {
        am[rg] = amp[rb + rg];
        at[rg] = att[rb + rg];
    }
#pragma unroll
    for (int jt = 0; jt < 4; ++jt) {
        int j = jt * 16 + lr;
        float b = bc[j];
#pragma unroll
        for (int rg = 0; rg < 4; ++rg) {
            int r = rb + rg;
            if (r < N) {
                out[(size_t)r * 64 + j] =
                    accP[jt][rg] + am[rg] * accA[jt][rg] +
                    at[rg] * accT[jt][rg] + b;
            }
        }
    }
}

// ---------------------------------------------------------------------------
static inline char* alignup(char* p, size_t a)
{
    return (char*)(((uintptr_t)p + a - 1) & ~(uintptr_t)(a - 1));
}

extern "C" void kernel_launch(void* const* d_in, const int* in_sizes, int n_in,
                              void* d_out, int out_size, void* d_ws, size_t ws_size,
                              hipStream_t stream)
{
    const float* x      = (const float*)d_in[0];
    const int*   ei     = (const int*)d_in[1];
    const float* pre_w  = (const float*)d_in[2];
    const float* pre_b  = (const float*)d_in[3];
    const float* post_w = (const float*)d_in[4];
    const float* post_b = (const float*)d_in[5];
    const float* lin_w  = (const float*)d_in[6];
    const float* lin_b  = (const float*)d_in[7];
    float* out = (float*)d_out;

    const int N = in_sizes[0] / 64;
    const int E = in_sizes[1] / 2;
    const int Npad = (N + 127) & ~127;       // aggs padding
    const int NWB2 = ((N + 63) & ~63) / 64;  // pre-MLP grid (64 nodes/block)
    const int NWBG = NWB2;                   // gemm grid (64 nodes/block)
    const int NBUCK = (N + 255) >> 8;
    if (N > 65536) return;               // 16-bit src packing + bucket bound

    size_t need = 0;
    auto acct = [&](size_t bytes) { need = ((need + 255) & ~(size_t)255) + bytes; };
    acct((size_t)N * 64 * 2);                // Ab
    acct((size_t)N * 64 * 2);                // Bb
    acct((size_t)Npad * 256 * 2);            // aggs
    acct(104 * 512 * 2);                     // Wp
    acct(64 * 4);                            // bc
    acct((size_t)Npad * 4);                  // amp
    acct((size_t)Npad * 4);                  // att
    acct(((size_t)N + 1) * 4);               // offsets
    acct((size_t)E * 2);                     // csr16
    acct((size_t)E * 4);                     // staged
    acct(PART_BLOCKS * 256 * 4);             // hist
    acct(257 * 4);                           // bstart
    acct(4);                                 // avg_acc
    if (ws_size < need) return;

    char* p = (char*)d_ws;
    auto take = [&](size_t bytes) {
        p = alignup(p, 256);
        void* r = (void*)p;
        p += bytes;
        return r;
    };
    ushort* Ab      = (ushort*)take((size_t)N * 64 * 2);
    ushort* Bb      = (ushort*)take((size_t)N * 64 * 2);
    ushort* aggs    = (ushort*)take((size_t)Npad * 256 * 2);
    ushort* Wp      = (ushort*)take(104 * 512 * 2);
    float*  bc      = (float*)take(64 * 4);
    float*  amp     = (float*)take((size_t)Npad * 4);
    float*  att     = (float*)take((size_t)Npad * 4);
    int*    offsets = (int*)take(((size_t)N + 1) * 4);
    ushort* csr16   = (ushort*)take((size_t)E * 2);
    uint*   staged  = (uint*)take((size_t)E * 4);
    int*    hist    = (int*)take(PART_BLOCKS * 256 * 4);
    int*    bstart  = (int*)take(257 * 4);
    float*  avg_acc = (float*)take(4);

    k_preh<<<NWB2 + PART_BLOCKS + FP_BLOCKS, 256, 0, stream>>>(
        x, pre_w, pre_b, ei, post_w, post_b, lin_w, lin_b,
        Ab, Bb, hist, Wp, bc, N, E, NWB2);
    k_part<<<PART_BLOCKS, 256, 0, stream>>>(ei, hist, bstart, staged,
                                            offsets, avg_acc, E, N);
    k_place<<<NBUCK, 256, 0, stream>>>(staged, bstart, csr16, offsets,
                                       avg_acc, N);
    k_aggregate<<<(N + 3) / 4, 256, 0, stream>>>(Ab, Bb, offsets, csr16,
                                                 avg_acc, aggs, amp, att, N);
    k_out_gemm<<<NWBG, 256, 0, stream>>>(x, aggs, amp, att, Wp, bc, out, N);
}

// Round 12
// 182.346 us; speedup vs baseline: 1.1633x; 1.1633x over previous
//
#include <hip/hip_runtime.h>
#include <math.h>
#include <stdint.h>

#define EPS 1e-5f

typedef __attribute__((ext_vector_type(8))) short bf16x8;
typedef __attribute__((ext_vector_type(4))) float f32x4;

union FragU {
    bf16x8 v;
    ushort u[8];
};

__device__ __forceinline__ ushort f2bf(float f)
{
    union { float f; uint u; } v; v.f = f;
    uint r = v.u + 0x7FFF + ((v.u >> 16) & 1);   // RNE
    return (ushort)(r >> 16);
}
__device__ __forceinline__ float bf2f(ushort u)
{
    union { uint u; float f; } v; v.u = (uint)u << 16;
    return v.f;
}
__device__ __forceinline__ uint packbf2(float lo, float hi)
{
    return (uint)f2bf(lo) | ((uint)f2bf(hi) << 16);
}

#define MFMA(a, b, c) __builtin_amdgcn_mfma_f32_16x16x32_bf16((a), (b), (c), 0, 0, 0)

#define PART_BLOCKS 128   // partition chunks (hist role / k_part must agree)
#define FP_BLOCKS   209   // fuse-pack role blocks (209*4 = 836 >= 833 units)

// 256-thread block exclusive scan; also returns block total.
__device__ __forceinline__ int blockScanExcl(int v, int* wsum, int* tot)
{
    int lane = threadIdx.x & 63, wv = threadIdx.x >> 6;
    int inc = v;
#pragma unroll
    for (int off = 1; off < 64; off <<= 1) {
        int u = __shfl_up(inc, off);
        if (lane >= off) inc += u;
    }
    __syncthreads();
    if (lane == 63) wsum[wv] = inc;
    __syncthreads();
    int add = 0;
#pragma unroll
    for (int i = 0; i < 4; ++i)
        if (i < wv) add += wsum[i];
    *tot = wsum[0] + wsum[1] + wsum[2] + wsum[3];
    return inc + add - v;
}

// ---------------------------------------------------------------------------
// K_preh: triple-role kernel (all roles independent).
//  [0, NWB2):                pre-MLP MFMA, 16 nodes/wave (64/block).
//                            Also stores x A-frags to xb (gemm reuses them).
//  [NWB2, NWB2+PART):        per-chunk LDS histogram of dst>>8.
//  [NWB2+PART, +FP_BLOCKS):  fuse post@lin -> Wp bf16 B-frags; bc.
// ---------------------------------------------------------------------------
__global__ __launch_bounds__(256) void k_preh(
    const float* __restrict__ x, const float* __restrict__ pre_w,
    const float* __restrict__ pre_b, const int* __restrict__ ei,
    const float* __restrict__ post_w, const float* __restrict__ post_b,
    const float* __restrict__ lin_w, const float* __restrict__ lin_b,
    ushort* __restrict__ Ab, ushort* __restrict__ Bb, ushort* __restrict__ xb,
    int* __restrict__ hist, ushort* __restrict__ Wp, float* __restrict__ bc,
    int N, int E, int NWB2)
{
    int t = threadIdx.x;

    if (blockIdx.x >= NWB2 + PART_BLOCKS) {
        // ---- fuse-pack role ----
        int unit = (blockIdx.x - NWB2 - PART_BLOCKS) * 4 + (t >> 6);
        int j = t & 63;
        if (unit > 832) return;
        if (unit < 832) {
            int r = unit;
            float acc = 0.f;
            for (int k = 0; k < 64; ++k)
                acc = fmaf(post_w[r * 64 + k], lin_w[k * 64 + j], acc);
            int tile, kk;
            if (r < 64) { tile = (r >> 5) * 4 + (j >> 4); kk = r & 31; }
            else {
                int g = (r - 64) >> 8, ka = (r - 64) & 255;
                tile = 8 + (g * 8 + (ka >> 5)) * 4 + (j >> 4); kk = ka & 31;
            }
            int ln = (j & 15) | ((kk >> 3) << 4);
            Wp[tile * 512 + ln * 8 + (kk & 7)] = f2bf(acc);
        } else {
            float a = lin_b[j];
            for (int k = 0; k < 64; ++k)
                a = fmaf(post_b[k], lin_w[k * 64 + j], a);
            bc[j] = a;
        }
        return;
    }

    if (blockIdx.x >= NWB2) {
        // ---- histogram role ----
        __shared__ int lh[256];
        int blk = blockIdx.x - NWB2;
        lh[t] = 0;
        __syncthreads();
        int chunk = (E + PART_BLOCKS - 1) / PART_BLOCKS;
        int c0 = blk * chunk, c1 = min(E, c0 + chunk);
        for (int e = c0 + t; e < c1; e += 256) {
            int dst = ei[E + e];
            if ((unsigned)dst < (unsigned)N) atomicAdd(&lh[dst >> 8], 1);
        }
        __syncthreads();
        hist[blk * 256 + t] = lh[t];
        return;
    }

    // ---- pre-MLP role: 64 nodes/block, 16 nodes/wave ----
    __shared__ ushort pw[16 * 512];
    for (int idx = t; idx < 8192; idx += 256) {
        int kin = idx >> 7, o = idx & 127;
        float v = (o < 64) ? pre_w[kin * 64 + o]
                           : pre_w[(64 + kin) * 64 + (o - 64)];
        int kk = kin & 31;
        int tile = (kin >> 5) * 8 + (o >> 4);
        int ln = (o & 15) | ((kk >> 3) << 4);
        pw[tile * 512 + ln * 8 + (kk & 7)] = f2bf(v);
    }
    __syncthreads();

    int w = t >> 6, lane = t & 63;
    int nb = blockIdx.x * 64 + w * 16;
    if (nb >= N) return;
    int lr = lane & 15, lk = lane >> 4;

    f32x4 acc[8] = {};
#pragma unroll
    for (int ks = 0; ks < 2; ++ks) {
        FragU A0;
        {
            int r0 = min(nb + lr, N - 1);
            const float* p0 = &x[r0 * 64 + ks * 32 + lk * 8];
            float4 a0 = *reinterpret_cast<const float4*>(p0);
            float4 a1 = *reinterpret_cast<const float4*>(p0 + 4);
            A0.u[0] = f2bf(a0.x); A0.u[1] = f2bf(a0.y);
            A0.u[2] = f2bf(a0.z); A0.u[3] = f2bf(a0.w);
            A0.u[4] = f2bf(a1.x); A0.u[5] = f2bf(a1.y);
            A0.u[6] = f2bf(a1.z); A0.u[7] = f2bf(a1.w);
        }
        // cache the x A-frag for the output GEMM (fragment order)
        *reinterpret_cast<bf16x8*>(
            &xb[(size_t)(nb >> 4) * 1024 + ks * 512 + lane * 8]) = A0.v;
#pragma unroll
        for (int jt = 0; jt < 8; ++jt) {
            bf16x8 B = *reinterpret_cast<const bf16x8*>(
                &pw[(ks * 8 + jt) * 512 + lane * 8]);
            acc[jt] = MFMA(A0.v, B, acc[jt]);
        }
    }
#pragma unroll
    for (int jt = 0; jt < 8; ++jt) {
        int o = jt * 16 + lr;
#pragma unroll
        for (int rg = 0; rg < 4; ++rg) {
            int r = nb + lk * 4 + rg;
            if (r < N) {
                float v = acc[jt][rg];
                if (o < 64) Ab[r * 64 + o] = f2bf(v + pre_b[o]);
                else        Bb[r * 64 + (o - 64)] = f2bf(v);
            }
        }
    }
}

// ---------------------------------------------------------------------------
// K_part: partition with inlined scans (round 10, unchanged).
// ---------------------------------------------------------------------------
__global__ __launch_bounds__(256) void k_part(
    const int* __restrict__ ei, const int* __restrict__ hist,
    int* __restrict__ bstart, uint* __restrict__ staged,
    int* __restrict__ offsets, float* __restrict__ avg_acc, int E, int N)
{
    __shared__ int cur[256];
    __shared__ int wsum[4];
    int t = threadIdx.x, blk = blockIdx.x;

    int pre = 0, tot = 0;
    for (int b = 0; b < PART_BLOCKS; ++b) {
        int h = hist[b * 256 + t];
        pre += (b < blk) ? h : 0;
        tot += h;
    }
    int grand;
    int bs = blockScanExcl(tot, wsum, &grand);
    cur[t] = bs + pre;
    if (blk == 0) {
        bstart[t] = bs;
        if (t == 255) { bstart[256] = grand; offsets[N] = grand; }
        if (t == 0) *avg_acc = 0.f;
    }
    __syncthreads();

    int chunk = (E + PART_BLOCKS - 1) / PART_BLOCKS;
    int c0 = blk * chunk, c1 = min(E, c0 + chunk);
    for (int e = c0 + t; e < c1; e += 256) {
        int src = ei[e];
        int dst = ei[E + e];
        if ((unsigned)dst < (unsigned)N) {
            if ((unsigned)src >= (unsigned)N) src = 0;
            int pos = atomicAdd(&cur[dst >> 8], 1);
            staged[pos] = (uint)src | ((uint)(dst & 255) << 16);
        }
    }
}

// ---------------------------------------------------------------------------
// K_place: one block per bucket (round 10, unchanged).
// ---------------------------------------------------------------------------
__global__ __launch_bounds__(256) void k_place(
    const uint* __restrict__ staged, const int* __restrict__ bucketStart,
    ushort* __restrict__ csr16, int* __restrict__ offsets,
    float* __restrict__ avg_acc, int N)
{
    __shared__ int cnt[256];
    __shared__ int wsum[4];
    __shared__ float fl[4];
    int t = threadIdx.x, lane = t & 63, wv = t >> 6;
    int b = blockIdx.x;
    int s0 = bucketStart[b], s1 = bucketStart[b + 1];

    cnt[t] = 0;
    __syncthreads();
    for (int i = s0 + t; i < s1; i += 256)
        atomicAdd(&cnt[(staged[i] >> 16) & 255], 1);
    __syncthreads();

    int d = cnt[t];
    int v = d;
#pragma unroll
    for (int off = 1; off < 64; off <<= 1) {
        int u = __shfl_up(v, off);
        if (lane >= off) v += u;
    }
    if (lane == 63) wsum[wv] = v;
    __syncthreads();
    int wvoff = 0;
#pragma unroll
    for (int i = 0; i < 4; ++i)
        if (i < wv) wvoff += wsum[i];
    int excl = wvoff + v - d;

    int node = b * 256 + t;
    if (node < N) offsets[node] = s0 + excl;

    float sl = (node < N) ? logf((float)d + 1.0f) : 0.f;
    for (int off = 32; off; off >>= 1) sl += __shfl_down(sl, off);
    if (lane == 0) fl[wv] = sl;

    cnt[t] = excl;            // placement cursor
    __syncthreads();
    if (t == 0) atomicAdd(avg_acc, fl[0] + fl[1] + fl[2] + fl[3]);

    for (int i = s0 + t; i < s1; i += 256) {
        uint ev = staged[i];
        int p = atomicAdd(&cnt[(ev >> 16) & 255], 1);
        csr16[s0 + p] = (ushort)(ev & 0xFFFFu);
    }
}

// ---------------------------------------------------------------------------
// K6: per-node aggregation, half-wave-per-edge, B-only statistics (round 8).
// ---------------------------------------------------------------------------
__global__ __launch_bounds__(256) void k_aggregate(
    const ushort* __restrict__ Ab, const ushort* __restrict__ Bb,
    const int* __restrict__ offsets, const ushort* __restrict__ csr16,
    const float* __restrict__ avg_sum, ushort* __restrict__ aggs,
    float* __restrict__ amp, float* __restrict__ att, int N)
{
    int wave = threadIdx.x >> 6, lane = threadIdx.x & 63;
    int n = blockIdx.x * 4 + wave;
    if (n >= N) return;

    int off0 = offsets[n], off1 = offsets[n + 1];
    int d = off1 - off0;
    int hl = lane & 31;          // feature-pair index
    int which = lane >> 5;       // 0 = even edge of pair, 1 = odd

    float s0 = 0.f, s1 = 0.f, q0 = 0.f, q1 = 0.f;
    float mn0 = 3.4e38f, mn1 = 3.4e38f, mx0 = -3.4e38f, mx1 = -3.4e38f;

#define UPD(bv)                                                         \
    {                                                                   \
        float m0 = bf2f((ushort)((bv) & 0xFFFFu));                      \
        float m1 = bf2f((ushort)((bv) >> 16));                          \
        s0 += m0; q0 = fmaf(m0, m0, q0);                                \
        mn0 = fminf(mn0, m0); mx0 = fmaxf(mx0, m0);                     \
        s1 += m1; q1 = fmaf(m1, m1, q1);                                \
        mn1 = fminf(mn1, m1); mx1 = fmaxf(mx1, m1);                     \
    }

    for (int base = off0; base < off1; base += 64) {
        int cnt = min(64, off1 - base);
        int s_idx = 0;
        if (lane < cnt) s_idx = (int)csr16[base + lane];
        int i = 0;
        for (; i + 15 < cnt; i += 16) {
            int sA = __shfl(s_idx, i + 0 + which);
            int sB = __shfl(s_idx, i + 2 + which);
            int sC = __shfl(s_idx, i + 4 + which);
            int sD = __shfl(s_idx, i + 6 + which);
            int sE = __shfl(s_idx, i + 8 + which);
            int sF = __shfl(s_idx, i + 10 + which);
            int sG = __shfl(s_idx, i + 12 + which);
            int sH = __shfl(s_idx, i + 14 + which);
            uint bA = *reinterpret_cast<const uint*>(&Bb[(size_t)sA * 64 + hl * 2]);
            uint bB = *reinterpret_cast<const uint*>(&Bb[(size_t)sB * 64 + hl * 2]);
            uint bC = *reinterpret_cast<const uint*>(&Bb[(size_t)sC * 64 + hl * 2]);
            uint bD = *reinterpret_cast<const uint*>(&Bb[(size_t)sD * 64 + hl * 2]);
            uint bE = *reinterpret_cast<const uint*>(&Bb[(size_t)sE * 64 + hl * 2]);
            uint bF = *reinterpret_cast<const uint*>(&Bb[(size_t)sF * 64 + hl * 2]);
            uint bG = *reinterpret_cast<const uint*>(&Bb[(size_t)sG * 64 + hl * 2]);
            uint bH = *reinterpret_cast<const uint*>(&Bb[(size_t)sH * 64 + hl * 2]);
            UPD(bA); UPD(bB); UPD(bC); UPD(bD);
            UPD(bE); UPD(bF); UPD(bG); UPD(bH);
        }
        for (; i + 7 < cnt; i += 8) {
            int sA = __shfl(s_idx, i + 0 + which);
            int sB = __shfl(s_idx, i + 2 + which);
            int sC = __shfl(s_idx, i + 4 + which);
            int sD = __shfl(s_idx, i + 6 + which);
            uint bA = *reinterpret_cast<const uint*>(&Bb[(size_t)sA * 64 + hl * 2]);
            uint bB = *reinterpret_cast<const uint*>(&Bb[(size_t)sB * 64 + hl * 2]);
            uint bC = *reinterpret_cast<const uint*>(&Bb[(size_t)sC * 64 + hl * 2]);
            uint bD = *reinterpret_cast<const uint*>(&Bb[(size_t)sD * 64 + hl * 2]);
            UPD(bA); UPD(bB); UPD(bC); UPD(bD);
        }
        for (; i < cnt; i += 2) {
            int sj = __shfl(s_idx, i + which);
            uint bv = *reinterpret_cast<const uint*>(&Bb[(size_t)sj * 64 + hl * 2]);
            if ((which == 0) | (i + 1 < cnt)) UPD(bv);
        }
    }
#undef UPD

    // combine half-waves
    s0 += __shfl_xor(s0, 32);  s1 += __shfl_xor(s1, 32);
    q0 += __shfl_xor(q0, 32);  q1 += __shfl_xor(q1, 32);
    mn0 = fminf(mn0, __shfl_xor(mn0, 32));
    mn1 = fminf(mn1, __shfl_xor(mn1, 32));
    mx0 = fmaxf(mx0, __shfl_xor(mx0, 32));
    mx1 = fmaxf(mx1, __shfl_xor(mx1, 32));

    uint av = *reinterpret_cast<const uint*>(&Ab[(size_t)n * 64 + hl * 2]);
    float a0 = bf2f((ushort)(av & 0xFFFFu));
    float a1 = bf2f((ushort)(av >> 16));

    float dc = (d > 0) ? (float)d : 1.0f;
    float mB0 = s0 / dc, mB1 = s1 / dc;
    float std0 = sqrtf(fmaxf(q0 / dc - mB0 * mB0, 0.f) + EPS);
    float std1 = sqrtf(fmaxf(q1 / dc - mB1 * mB1, 0.f) + EPS);
    float mean0 = a0 + mB0, mean1 = a1 + mB1;
    float mnF0 = a0 + mn0, mnF1 = a1 + mn1;
    float mxF0 = a0 + mx0, mxF1 = a1 + mx1;
    if (d == 0) {
        mean0 = mean1 = 0.f;
        mnF0 = mnF1 = 0.f;
        mxF0 = mxF1 = 0.f;
    }

    if (lane < 32) {
        uint* ag = reinterpret_cast<uint*>(&aggs[(size_t)n * 256]);
        ag[0 * 32 + hl] = packbf2(mean0, mean1);
        ag[1 * 32 + hl] = packbf2(mnF0, mnF1);
        ag[2 * 32 + hl] = packbf2(mxF0, mxF1);
        ag[3 * 32 + hl] = packbf2(std0, std1);
    }
    if (lane == 0) {
        float avg = *avg_sum / (float)N;
        float dlog = logf(dc + 1.0f);
        amp[n] = dlog / avg;
        att[n] = avg / dlog;
    }
}

// ---------------------------------------------------------------------------
// K7: output GEMM via bf16 MFMA — 32 nodes/wave (round 10) with xb A-frags.
// ---------------------------------------------------------------------------
__global__ __launch_bounds__(256) void k_out_gemm(
    const ushort* __restrict__ xb, const ushort* __restrict__ aggs,
    const float* __restrict__ amp, const float* __restrict__ att,
    const ushort* __restrict__ Wp, const float* __restrict__ bc,
    float* __restrict__ out, int N)
{
    int w = threadIdx.x >> 6, lane = threadIdx.x & 63;
    int nb = (blockIdx.x * 4 + w) * 32;
    int lr = lane & 15, lk = lane >> 4;

    f32x4 accP[2][4] = {};
    f32x4 accA[2][4] = {};
    f32x4 accT[2][4] = {};

    // ---- x chunk (K=64, W0 only): A-frags precomputed in k_preh ----
#pragma unroll
    for (int ks = 0; ks < 2; ++ks) {
        bf16x8 A0 = *reinterpret_cast<const bf16x8*>(
            &xb[(size_t)(nb >> 4) * 1024 + ks * 512 + lane * 8]);
        bf16x8 A1 = *reinterpret_cast<const bf16x8*>(
            &xb[(size_t)((nb >> 4) + 1) * 1024 + ks * 512 + lane * 8]);
#pragma unroll
        for (int jt = 0; jt < 4; ++jt) {
            bf16x8 B = *reinterpret_cast<const bf16x8*>(
                &Wp[(ks * 4 + jt) * 512 + lane * 8]);
            accP[0][jt] = MFMA(A0, B, accP[0][jt]);
            accP[1][jt] = MFMA(A1, B, accP[1][jt]);
        }
    }

    // ---- aggs chunks (K=256, W1/W2/W3) ----
#pragma unroll 2
    for (int ks = 0; ks < 8; ++ks) {
        bf16x8 A0 = *reinterpret_cast<const bf16x8*>(
            &aggs[(size_t)(nb + lr) * 256 + ks * 32 + lk * 8]);
        bf16x8 A1 = *reinterpret_cast<const bf16x8*>(
            &aggs[(size_t)(nb + 16 + lr) * 256 + ks * 32 + lk * 8]);
        bf16x8 B0[4], B1[4], B2[4];
#pragma unroll
        for (int jt = 0; jt < 4; ++jt) {
            B0[jt] = *reinterpret_cast<const bf16x8*>(
                &Wp[(8 + (0 * 8 + ks) * 4 + jt) * 512 + lane * 8]);
            B1[jt] = *reinterpret_cast<const bf16x8*>(
                &Wp[(8 + (1 * 8 + ks) * 4 + jt) * 512 + lane * 8]);
            B2[jt] = *reinterpret_cast<const bf16x8*>(
                &Wp[(8 + (2 * 8 + ks) * 4 + jt) * 512 + lane * 8]);
        }
#pragma unroll
        for (int jt = 0; jt < 4; ++jt) {
            accP[0][jt] = MFMA(A0, B0[jt], accP[0][jt]);
            accP[1][jt] = MFMA(A1, B0[jt], accP[1][jt]);
            accA[0][jt] = MFMA(A0, B1[jt], accA[0][jt]);
            accA[1][jt] = MFMA(A1, B1[jt], accA[1][jt]);
            accT[0][jt] = MFMA(A0, B2[jt], accT[0][jt]);
            accT[1][jt] = MFMA(A1, B2[jt], accT[1][jt]);
        }
    }

#pragma unroll
    for (int mt = 0; mt < 2; ++mt) {
        int rb = nb + mt * 16 + lk * 4;
        float am[4], at[4];
#pragma unroll
        for (int rg = 0; rg < 4; ++rg) {
            am[rg] = amp[rb + rg];
            at[rg] = att[rb + rg];
        }
#pragma unroll
        for (int jt = 0; jt < 4; ++jt) {
            int j = jt * 16 + lr;
            float b = bc[j];
#pragma unroll
            for (int rg = 0; rg < 4; ++rg) {
                int r = rb + rg;
                if (r < N) {
                    out[(size_t)r * 64 + j] =
                        accP[mt][jt][rg] + am[rg] * accA[mt][jt][rg] +
                        at[rg] * accT[mt][jt][rg] + b;
                }
            }
        }
    }
}

// ---------------------------------------------------------------------------
static inline char* alignup(char* p, size_t a)
{
    return (char*)(((uintptr_t)p + a - 1) & ~(uintptr_t)(a - 1));
}

extern "C" void kernel_launch(void* const* d_in, const int* in_sizes, int n_in,
                              void* d_out, int out_size, void* d_ws, size_t ws_size,
                              hipStream_t stream)
{
    const float* x      = (const float*)d_in[0];
    const int*   ei     = (const int*)d_in[1];
    const float* pre_w  = (const float*)d_in[2];
    const float* pre_b  = (const float*)d_in[3];
    const float* post_w = (const float*)d_in[4];
    const float* post_b = (const float*)d_in[5];
    const float* lin_w  = (const float*)d_in[6];
    const float* lin_b  = (const float*)d_in[7];
    float* out = (float*)d_out;

    const int N = in_sizes[0] / 64;
    const int E = in_sizes[1] / 2;
    const int Npad = (N + 127) & ~127;       // aggs/xb padding (128)
    const int NWB  = Npad / 128;             // gemm grid (128 nodes/block)
    const int NWB2 = ((N + 63) & ~63) / 64;  // pre-MLP grid (64 nodes/block)
    const int NBUCK = (N + 255) >> 8;
    if (N > 65536) return;               // 16-bit src packing + bucket bound

    size_t need = 0;
    auto acct = [&](size_t bytes) { need = ((need + 255) & ~(size_t)255) + bytes; };
    acct((size_t)N * 64 * 2);                // Ab
    acct((size_t)N * 64 * 2);                // Bb
    acct((size_t)Npad * 128);                // xb (x A-frags, bf16)
    acct((size_t)Npad * 256 * 2);            // aggs
    acct(104 * 512 * 2);                     // Wp
    acct(64 * 4);                            // bc
    acct((size_t)Npad * 4);                  // amp
    acct((size_t)Npad * 4);                  // att
    acct(((size_t)N + 1) * 4);               // offsets
    acct((size_t)E * 2);                     // csr16
    acct((size_t)E * 4);                     // staged
    acct(PART_BLOCKS * 256 * 4);             // hist
    acct(257 * 4);                           // bstart
    acct(4);                                 // avg_acc
    if (ws_size < need) return;

    char* p = (char*)d_ws;
    auto take = [&](size_t bytes) {
        p = alignup(p, 256);
        void* r = (void*)p;
        p += bytes;
        return r;
    };
    ushort* Ab      = (ushort*)take((size_t)N * 64 * 2);
    ushort* Bb      = (ushort*)take((size_t)N * 64 * 2);
    ushort* xb      = (ushort*)take((size_t)Npad * 128);
    ushort* aggs    = (ushort*)take((size_t)Npad * 256 * 2);
    ushort* Wp      = (ushort*)take(104 * 512 * 2);
    float*  bc      = (float*)take(64 * 4);
    float*  amp     = (float*)take((size_t)Npad * 4);
    float*  att     = (float*)take((size_t)Npad * 4);
    int*    offsets = (int*)take(((size_t)N + 1) * 4);
    ushort* csr16   = (ushort*)take((size_t)E * 2);
    uint*   staged  = (uint*)take((size_t)E * 4);
    int*    hist    = (int*)take(PART_BLOCKS * 256 * 4);
    int*    bstart  = (int*)take(257 * 4);
    float*  avg_acc = (float*)take(4);

    k_preh<<<NWB2 + PART_BLOCKS + FP_BLOCKS, 256, 0, stream>>>(
        x, pre_w, pre_b, ei, post_w, post_b, lin_w, lin_b,
        Ab, Bb, xb, hist, Wp, bc, N, E, NWB2);
    k_part<<<PART_BLOCKS, 256, 0, stream>>>(ei, hist, bstart, staged,
                                            offsets, avg_acc, E, N);
    k_place<<<NBUCK, 256, 0, stream>>>(staged, bstart, csr16, offsets,
                                       avg_acc, N);
    k_aggregate<<<(N + 3) / 4, 256, 0, stream>>>(Ab, Bb, offsets, csr16,
                                                 avg_acc, aggs, amp, att, N);
    k_out_gemm<<<NWB, 256, 0, stream>>>(xb, aggs, amp, att, Wp, bc, out, N);
}